// Round 6
// baseline (501.433 us; speedup 1.0000x reference)
//
#include <hip/hip_runtime.h>
#include <math.h>

#define BLOCK 1024
#define NWAVES (BLOCK / 64)   // 16 waves
#define NV 8                  // float4 per thread: 1024*8*4 = 32768 >= d
#define CAND_CAP 6144         // LDS candidate buffer (24 KB)
#define NREG 12               // wave0 register-resident candidates: 64*12 = 768

// Raw barrier: drains LDS ops only, NOT vmcnt -- the next row's global loads
// stay in flight across it. (__syncthreads emits s_waitcnt vmcnt(0) before
// s_barrier and would serialize the pipeline -- the m97 barrier-drain lesson.)
// All cross-wave state here is LDS, so lgkmcnt(0) is the sufficient drain.
#define BAR() asm volatile("s_waitcnt lgkmcnt(0)\n\ts_barrier" ::: "memory")

__device__ __forceinline__ float waveReduceMax(float v) {
#pragma unroll
    for (int off = 32; off > 0; off >>= 1)
        v = fmaxf(v, __shfl_down(v, off, 64));
    return v;
}
__device__ __forceinline__ float waveReduceSum(float v) {
#pragma unroll
    for (int off = 32; off > 0; off >>= 1)
        v += __shfl_down(v, off, 64);
    return v;
}

// ---- row load into a named register buffer (plain global loads) ----
__device__ __forceinline__ void issue_row_load(const float* __restrict__ xr,
                                               int t, int d, float4 (&r)[NV]) {
#pragma unroll
    for (int i = 0; i < NV; ++i) {
        int e = (i * BLOCK + t) * 4;
        if (e + 4 <= d) {
            r[i] = *reinterpret_cast<const float4*>(xr + e);
        } else {
            float4 v = make_float4(-INFINITY, -INFINITY, -INFINITY, -INFINITY);
            if (e < d)     v.x = xr[e];
            if (e + 1 < d) v.y = xr[e + 1];
            if (e + 2 < d) v.z = xr[e + 2];
            if (e + 3 < d) v.w = xr[e + 3];
            r[i] = v;
        }
    }
}

// ---- wave0 solve (proven exact R0-R5, absmax=0) ----
// s_cand holds u=(x-rowmax)/2; extras below tau are inert (0 in f, excluded
// from support). 18 bisection steps on f(tau)=sum max(u-tau,0)^2 (monotone,
// u=0 present => tau* in [-1,0]) then exact closed form on the support --
// identical to the reference's sorted-cumsum formula.
__device__ __forceinline__ void solve_wave0(const float* s_cand, int k,
                                            float rowmax, float xt,
                                            float inv_n, float* out, int lane)
{
    float ur[NREG];
#pragma unroll
    for (int j = 0; j < NREG; ++j) {
        int idx = lane + 64 * j;
        ur[j] = (idx < k) ? s_cand[idx] : -1e30f;   // sentinel: never in support
    }

    float lo = -1.0f, hi = 0.0f;
    for (int it = 0; it < 18; ++it) {
        float tau = 0.5f * (lo + hi);
        float acc = 0.0f;
#pragma unroll
        for (int j = 0; j < NREG; ++j) {
            float u = ur[j] - tau;
            acc += (u > 0.0f) ? u * u : 0.0f;
        }
        for (int j = 64 * NREG + lane; j < k; j += 64) {   // overflow tail
            float u = s_cand[j] - tau;
            if (u > 0.0f) acc += u * u;
        }
        float tot = waveReduceSum(acc);
        tot = __shfl(tot, 0, 64);
        if (tot >= 1.0f) lo = tau; else hi = tau;
    }
    const float tau_b = 0.5f * (lo + hi);

    float s1 = 0.0f, s2 = 0.0f, sc = 0.0f;
#pragma unroll
    for (int j = 0; j < NREG; ++j) {
        float u = ur[j];
        if (u > tau_b) { s1 += u; s2 += u * u; sc += 1.0f; }
    }
    for (int j = 64 * NREG + lane; j < k; j += 64) {
        float u = s_cand[j];
        if (u > tau_b) { s1 += u; s2 += u * u; sc += 1.0f; }
    }
    s1 = waveReduceSum(s1); s1 = __shfl(s1, 0, 64);
    s2 = waveReduceSum(s2); s2 = __shfl(s2, 0, 64);
    sc = waveReduceSum(sc); sc = __shfl(sc, 0, 64);
    float mean  = s1 / sc;
    float ss    = s2 - s1 * mean;
    float delta = (1.0f - ss) / sc;
    if (delta < 0.0f) delta = 0.0f;
    const float tau_star = mean - sqrtf(delta);

    float p32 = 0.0f, dot = 0.0f;
#pragma unroll
    for (int j = 0; j < NREG; ++j) {
        float u = ur[j] - tau_star;
        if (u > 0.0f) {
            float p = u * u;
            p32 += p * u;
            dot += p * (2.0f * ur[j] + rowmax);
        }
    }
    for (int j = 64 * NREG + lane; j < k; j += 64) {
        float uc = s_cand[j];
        float u  = uc - tau_star;
        if (u > 0.0f) {
            float p = u * u;
            p32 += p * u;
            dot += p * (2.0f * uc + rowmax);
        }
    }
    p32 = waveReduceSum(p32);
    dot = waveReduceSum(dot);
    if (lane == 0) {
        float loss = (1.0f - p32) * (4.0f / 3.0f) + dot - xt;
        atomicAdd(out, loss * inv_n);
    }
}

// ---- one row: max -> compact -> wave0 solve (raw BARs only) ----
__device__ __forceinline__ void process_row(
    const float4 (&r)[NV], float xt, float inv_n,
    int t, int lane, int wave,
    float* s_cand, float* s_red, int* s_cnt, float* s_bcast,
    float* __restrict__ out)
{
    // block max (auto-waitcnt here is vmcnt(<next-row loads>), not 0)
    float m = -INFINITY;
#pragma unroll
    for (int i = 0; i < NV; ++i)
        m = fmaxf(m, fmaxf(fmaxf(r[i].x, r[i].y), fmaxf(r[i].z, r[i].w)));
    m = waveReduceMax(m);
    if (lane == 0) s_red[wave] = m;
    BAR();
    if (wave == 0) {
        float v = (lane < NWAVES) ? s_red[lane] : -INFINITY;
        v = waveReduceMax(v);
        if (lane == 0) *s_bcast = v;
    }
    BAR();
    const float rowmax = *s_bcast;
    const float thr = rowmax - 2.0f;   // u >= -1 >= tau* superset

    // ballot-compact candidates to LDS
#pragma unroll
    for (int i = 0; i < NV; ++i) {
        float vals[4] = { r[i].x, r[i].y, r[i].z, r[i].w };
#pragma unroll
        for (int c = 0; c < 4; ++c) {
            float v = vals[c];
            bool pred = (v >= thr);
            unsigned long long mask = __ballot(pred);
            if (mask) {                               // wave-uniform branch
                int base;
                if (lane == 0) base = atomicAdd(s_cnt, __popcll(mask));
                base = __shfl(base, 0, 64);
                if (pred) {
                    int pos = base + (int)__popcll(mask & ((1ull << lane) - 1ull));
                    if (pos < CAND_CAP) s_cand[pos] = (v - rowmax) * 0.5f;
                }
            }
        }
    }
    BAR();

    // wave0 solves; waves 1-15 run ahead to the next row's vm-wait + max.
    // They cannot reach the next compact (s_cand/s_cnt writes) until wave0
    // joins the next max-phase BARs -- i.e. after this solve and the s_cnt
    // reset below, whose LDS write drains at wave0's next BAR.
    if (wave == 0) {
        const int k = min(*s_cnt, CAND_CAP);
        if (lane == 0) *s_cnt = 0;
        solve_wave0(s_cand, k, rowmax, xt, inv_n, out, lane);
    }
}

// Persistent blocks (grid = min(n,256), 1 block/CU), register double-buffer:
// iteration k consumes buffer cur (loads issued at iteration k-1) and FIRST
// issues row k+1's loads into the other buffer -- so HBM streams through the
// max/compact/solve phases. launch_bounds(1024,4): 128-VGPR budget; payload
// 2x32 + ~35 overhead fits without spill. Only the final row's solve is
// exposed (~2.5us per block).
__global__ __launch_bounds__(BLOCK, 4) void tsallis15_kernel(
    const float* __restrict__ x, const int* __restrict__ tgt,
    float* __restrict__ out, int n, int d, float inv_n)
{
    __shared__ float s_cand[CAND_CAP];
    __shared__ float s_red[NWAVES];
    __shared__ int   s_cnt;
    __shared__ float s_bcast;

    const int t    = threadIdx.x;
    const int lane = t & 63;
    const int wave = t >> 6;
    const int grid = gridDim.x;
    const int row0 = blockIdx.x;

    if (t == 0) s_cnt = 0;   // drained at the first max-phase BAR

    // prologue: issue row0's loads
    float4 bufA[NV], bufB[NV];
    issue_row_load(x + (size_t)row0 * (size_t)d, t, d, bufA);

    // prologue: per-lane target-logit prefetch -- xt for this block's i-th row
    // lives in wave0 lane i (fetched via __shfl at use; no late global load in
    // the solve).
    float xt_pre = 0.0f;
    if (wave == 0) {
        int rr = row0 + lane * grid;
        if (rr < n) xt_pre = x[(size_t)rr * (size_t)d + tgt[rr]];
    }

    int iter = 0;
    for (int row = row0; row < n; row += grid, ++iter) {
        const int nextrow = row + grid;
        float xt;
        if (iter < 64) {
            xt = __shfl(xt_pre, iter, 64);
        } else {            // >16K-row fallback (not hit at n=2048)
            xt = 0.0f;
            if (t == 0) xt = x[(size_t)row * (size_t)d + tgt[row]];
        }
        if ((iter & 1) == 0) {
            if (nextrow < n)
                issue_row_load(x + (size_t)nextrow * (size_t)d, t, d, bufB);
            process_row(bufA, xt, inv_n, t, lane, wave,
                        s_cand, s_red, &s_cnt, &s_bcast, out);
        } else {
            if (nextrow < n)
                issue_row_load(x + (size_t)nextrow * (size_t)d, t, d, bufA);
            process_row(bufB, xt, inv_n, t, lane, wave,
                        s_cand, s_red, &s_cnt, &s_bcast, out);
        }
    }
}

extern "C" void kernel_launch(void* const* d_in, const int* in_sizes, int n_in,
                              void* d_out, int out_size, void* d_ws, size_t ws_size,
                              hipStream_t stream) {
    const float* x   = (const float*)d_in[0];
    const int*   tgt = (const int*)d_in[1];
    float*       out = (float*)d_out;

    const int n = in_sizes[1];
    const int d = in_sizes[0] / n;

    hipMemsetAsync(out, 0, (size_t)out_size * sizeof(float), stream);
    const int grid = (n < 256) ? n : 256;
    tsallis15_kernel<<<grid, BLOCK, 0, stream>>>(x, tgt, out, n, d, 1.0f / (float)n);
}

// Round 7
// 413.961 us; speedup vs baseline: 1.2113x; 1.2113x over previous
//
#include <hip/hip_runtime.h>
#include <math.h>

#define BLOCK 1024
#define HALF  512             // threads per row-group (waves 0-7 / 8-15)
#define NWAVES 16
#define NV    16              // float4 per thread per row: 512*16*4 = 32768 >= d
#define CAPH  4096            // per-row LDS candidate cap (16 KB each)
#define NREG  8               // solver register candidates: 64*8 = 512 (typ k~370)

__device__ __forceinline__ float waveReduceMax(float v) {
#pragma unroll
    for (int off = 32; off > 0; off >>= 1)
        v = fmaxf(v, __shfl_down(v, off, 64));
    return v;
}
__device__ __forceinline__ float waveReduceSum(float v) {
#pragma unroll
    for (int off = 32; off > 0; off >>= 1)
        v += __shfl_down(v, off, 64);
    return v;
}

// ---- wave solve (proven exact R0-R6, absmax=0) ----
// s_cand holds u=(x-rowmax)/2 (k entries; sub-threshold extras are inert:
// they contribute 0 to f(tau) on [-1,0] and self-exclude from the support).
// Runs on ONE wave. 18 bisection steps on f(tau)=sum max(u-tau,0)^2
// (monotone; u=0 present => f(-1)>=1>=f(0), tau* in [-1,0]), then the exact
// closed form tau* = mean - sqrt((1-ss)/k) on the identified support --
// identical to the reference's sorted-cumsum formula.
__device__ __forceinline__ void solve_wave(const float* s_cand, int k,
                                           float rowmax, float xt,
                                           float inv_n, float* out, int lane)
{
    float ur[NREG];
#pragma unroll
    for (int j = 0; j < NREG; ++j) {
        int idx = lane + 64 * j;
        ur[j] = (idx < k) ? s_cand[idx] : -1e30f;   // sentinel: never in support
    }

    float lo = -1.0f, hi = 0.0f;
    for (int it = 0; it < 18; ++it) {
        float tau = 0.5f * (lo + hi);
        float acc = 0.0f;
#pragma unroll
        for (int j = 0; j < NREG; ++j) {
            float u = ur[j] - tau;
            acc += (u > 0.0f) ? u * u : 0.0f;
        }
        for (int j = 64 * NREG + lane; j < k; j += 64) {   // overflow tail
            float u = s_cand[j] - tau;
            if (u > 0.0f) acc += u * u;
        }
        float tot = waveReduceSum(acc);
        tot = __shfl(tot, 0, 64);
        if (tot >= 1.0f) lo = tau; else hi = tau;
    }
    const float tau_b = 0.5f * (lo + hi);

    float s1 = 0.0f, s2 = 0.0f, sc = 0.0f;
#pragma unroll
    for (int j = 0; j < NREG; ++j) {
        float u = ur[j];
        if (u > tau_b) { s1 += u; s2 += u * u; sc += 1.0f; }
    }
    for (int j = 64 * NREG + lane; j < k; j += 64) {
        float u = s_cand[j];
        if (u > tau_b) { s1 += u; s2 += u * u; sc += 1.0f; }
    }
    s1 = waveReduceSum(s1); s1 = __shfl(s1, 0, 64);
    s2 = waveReduceSum(s2); s2 = __shfl(s2, 0, 64);
    sc = waveReduceSum(sc); sc = __shfl(sc, 0, 64);
    float mean  = s1 / sc;
    float ss    = s2 - s1 * mean;              // sum of squared deviations
    float delta = (1.0f - ss) / sc;
    if (delta < 0.0f) delta = 0.0f;
    const float tau_star = mean - sqrtf(delta);

    float p32 = 0.0f, dot = 0.0f;
#pragma unroll
    for (int j = 0; j < NREG; ++j) {
        float u = ur[j] - tau_star;
        if (u > 0.0f) {
            float p = u * u;
            p32 += p * u;
            dot += p * (2.0f * ur[j] + rowmax);
        }
    }
    for (int j = 64 * NREG + lane; j < k; j += 64) {
        float uc = s_cand[j];
        float u  = uc - tau_star;
        if (u > 0.0f) {
            float p = u * u;
            p32 += p * u;
            dot += p * (2.0f * uc + rowmax);
        }
    }
    p32 = waveReduceSum(p32);
    dot = waveReduceSum(dot);
    if (lane == 0) {
        float loss = (1.0f - p32) * (4.0f / 3.0f) + dot - xt;
        atomicAdd(out, loss * inv_n);
    }
}

// DUAL-ROW blocks: 1024 threads; waves 0-7 own row 2b, waves 8-15 own row
// 2b+1 (512 threads x NV=16 float4 = 32768 floats per row, registers, single
// HBM pass). One set of block-wide barriers serves BOTH rows (both halves
// arrive at the same __syncthreads), and the two solves run CONCURRENTLY on
// wave 0 and wave 8 (different SIMDs). Rationale (R0-R6 ladder): the
// monolithic 1-row kernel (R4, 62us) pays ~2.5us of barrier/compact/solve
// overhead per 128 KB round at 1 block/CU (67% HBM duty); every cross-block /
// cross-iteration overlap attempt failed (R2 lockstep, R3 LDS pipeline 3x,
// R5 split, R6 dbuf spill: VGPR=64 + 89MB scratch writes). This keeps the
// proven structure and amortizes the same overhead over 256 KB instead.
// Flat code, no array-ref helpers (R6's allocation failure mode); payload 64
// VGPR + ~30 temps < 128 budget at launch_bounds(1024,4); solver ur[] reuses
// dead r[] regs.
__global__ __launch_bounds__(BLOCK, 4) void tsallis15_kernel(
    const float* __restrict__ x, const int* __restrict__ tgt,
    float* __restrict__ out, int n, int d, float inv_n)
{
    __shared__ float s_cand[2][CAPH];   // 32 KB
    __shared__ float s_red[NWAVES];
    __shared__ float s_max[2];
    __shared__ int   s_cnt[2];

    const int t    = threadIdx.x;
    const int lane = t & 63;
    const int wave = t >> 6;
    const int half = wave >> 3;          // 0: row A, 1: row B
    const int th   = t & (HALF - 1);     // thread index within the half
    const int row  = blockIdx.x * 2 + half;
    const bool rv  = (row < n);          // n odd => half 1 of last block idle
    const float* __restrict__ xr = x + (size_t)row * (size_t)d;
    const float4* __restrict__ xr4 = reinterpret_cast<const float4*>(xr);
    const int d4 = d >> 2;

    if (t < 2) s_cnt[t] = 0;

    // hoisted target-logit chain (t==0 -> row A, t==512 -> wave8 lane0 -> row B);
    // issued first, consumed last, latency hidden under the row pass
    float xt = 0.0f;
    if (th == 0 && rv) xt = xr[tgt[row]];

    // ---- single HBM pass: half-block's row -> registers ----
    float4 r[NV];
#pragma unroll
    for (int i = 0; i < NV; ++i) {
        int idx = i * HALF + th;                       // float4 index in row
        r[i] = (rv && idx < d4)
             ? xr4[idx]
             : make_float4(-INFINITY, -INFINITY, -INFINITY, -INFINITY);
    }
    float tailv = -INFINITY;                           // d%4 tail (0-trip here)
    {
        int e = (d4 << 2) + th;
        if (rv && e < d && th < (d & 3) + 1) tailv = xr[e];  // th<=d%4 guard
    }
    // NOTE: simpler exact guard: only th < (d - (d4<<2)) lanes have a tail elem
    // (the condition above admits th == d%4 too, but e<d already excludes it)

    // ---- per-row block max (both halves share the same barriers) ----
    float m = tailv;
#pragma unroll
    for (int i = 0; i < NV; ++i)
        m = fmaxf(m, fmaxf(fmaxf(r[i].x, r[i].y), fmaxf(r[i].z, r[i].w)));
    m = waveReduceMax(m);
    if (lane == 0) s_red[wave] = m;
    __syncthreads();
    if ((wave & 7) == 0) {               // wave 0 reduces half 0, wave 8 half 1
        float v = (lane < 8) ? s_red[half * 8 + lane] : -INFINITY;
        v = waveReduceMax(v);
        if (lane == 0) s_max[half] = v;
    }
    __syncthreads();
    const float rowmax = s_max[half];
    const float thr = rowmax - 2.0f;     // u = (x-rowmax)/2 >= -1 >= tau*

    // ---- candidate filter via per-wave ballot compaction ----
    // (each wave lies entirely within one half: ballots are row-coherent)
    float* s_c = s_cand[half];
    int*   s_k = &s_cnt[half];
#pragma unroll
    for (int i = 0; i < NV; ++i) {
        float4 v = r[i];
        float mx4 = fmaxf(fmaxf(v.x, v.y), fmaxf(v.z, v.w));
        unsigned long long any = __ballot(mx4 >= thr);
        if (any) {                                     // wave-uniform branch
            float vals[4] = { v.x, v.y, v.z, v.w };
#pragma unroll
            for (int c = 0; c < 4; ++c) {
                float vv = vals[c];
                bool pred = (vv >= thr);
                unsigned long long mask = __ballot(pred);
                if (mask) {
                    int base;
                    if (lane == 0) base = atomicAdd(s_k, __popcll(mask));
                    base = __shfl(base, 0, 64);
                    if (pred) {
                        int pos = base + (int)__popcll(mask & ((1ull << lane) - 1ull));
                        if (pos < CAPH) s_c[pos] = (vv - rowmax) * 0.5f;
                    }
                }
            }
        }
    }
    {   // scalar tail (0-trip when d%4==0)
        bool pred = (tailv >= thr);
        unsigned long long mask = __ballot(pred);
        if (mask) {
            int base;
            if (lane == 0) base = atomicAdd(s_k, __popcll(mask));
            base = __shfl(base, 0, 64);
            if (pred) {
                int pos = base + (int)__popcll(mask & ((1ull << lane) - 1ull));
                if (pos < CAPH) s_c[pos] = (tailv - rowmax) * 0.5f;
            }
        }
    }
    __syncthreads();

    // ---- concurrent solves: wave 0 -> row A, wave 8 -> row B ----
    if ((wave & 7) == 0 && rv) {
        const int k = min(*s_k, CAPH);
        solve_wave(s_c, k, rowmax, xt, inv_n, out, lane);
    }
}

extern "C" void kernel_launch(void* const* d_in, const int* in_sizes, int n_in,
                              void* d_out, int out_size, void* d_ws, size_t ws_size,
                              hipStream_t stream) {
    const float* x   = (const float*)d_in[0];
    const int*   tgt = (const int*)d_in[1];
    float*       out = (float*)d_out;

    const int n = in_sizes[1];
    const int d = in_sizes[0] / n;

    hipMemsetAsync(out, 0, (size_t)out_size * sizeof(float), stream);
    const int grid = (n + 1) / 2;
    tsallis15_kernel<<<grid, BLOCK, 0, stream>>>(x, tgt, out, n, d, 1.0f / (float)n);
}